// Round 6
// baseline (459.165 us; speedup 1.0000x reference)
//
#include <hip/hip_runtime.h>
#include <stdint.h>

// Resample2d: backward warp of input1 (B,C,H,W) by flow input2 (B,2,H,W).
// Bilinear, border padding (clamp). B=8 C=64 H=256 W=448, all fp32.
//
// Round 6: LDS-gather done right. Global gathers are TA-transaction bound
// (per-lane-random y0 -> ~6+ lines/instr); ds_read is scatter-immune.
// Fixes vs R5: global_load_lds width-16 staging (no prefetch VGPRs),
// NS=20-row window (35840 B -> 4 blocks/CU), __launch_bounds__(448,7)
// (VGPR<=73 -> 28/32 waves). Coords pre-packed (2 u32 + wx,wy per row).
// |fy|>6 outliers (P~2e-9) take a cold global fallback.

#define RB 8
#define RC 64
#define RH 256
#define RW 448
#define RHW (RH * RW)
#define TPB 448                    // 7 waves
#define ROWS 8                     // output rows per block
#define NS 20                      // staged rows: ROWS + 2*6 margin
#define CS 8                       // channel groups
#define CPB (RC / CS)              // 8 channels per block
#define YT (RH / ROWS)             // 32 y-tiles
#define NBLK (RB * CS * YT)        // 2048 blocks
#define NXCD 8
#define CHUNKF (TPB * 4)           // 1792 floats per staging chunk
#define NCHUNK (NS * RW / CHUNKF)  // 5 (exact)

#define GLOAD_LDS16(gp, lp)                                                   \
    __builtin_amdgcn_global_load_lds(                                         \
        (const __attribute__((address_space(1))) void*)(gp),                  \
        (__attribute__((address_space(3))) void*)(lp), 16, 0, 0)

__global__ __launch_bounds__(TPB, 7) void resample2d_kernel(
    const float* __restrict__ img,   // (B,C,H,W)
    const float* __restrict__ flow,  // (B,2,H,W)
    float* __restrict__ out)         // (B,C,H,W)
{
    __shared__ float sm[NS * RW];    // 35840 B

    // Bijective XCD-chunked swizzle (2048 % 8 == 0): consecutive ids sweep
    // y-tiles of one (b,cgroup) so staging-window overlap hits one XCD L2.
    int bid = blockIdx.x;
    const int chunk = NBLK / NXCD;               // 256
    int id = (bid & (NXCD - 1)) * chunk + (bid >> 3);

    int b  = id / (CS * YT);
    int rm = id % (CS * YT);
    int cg = rm / YT;
    int ybase = (rm % YT) * ROWS;
    int ys0 = min(max(ybase - 6, 0), RH - NS);   // staged window start row

    int tid = threadIdx.x;                        // == x column (0..447)

    // ---- Coord precompute: packed LDS float-indices + weights ----
    unsigned pkA[ROWS], pkB[ROWS];               // b00|b01<<16, b10|b11<<16
    float wxa[ROWS], wya[ROWS];
    const float* flb = flow + (size_t)b * 2 * RHW;
    #pragma unroll
    for (int r = 0; r < ROWS; ++r) {
        int y = ybase + r;
        float fx = flb[(size_t)y * RW + tid];
        float fy = flb[RHW + (size_t)y * RW + tid];
        float xr = fminf(fmaxf((float)tid + fx, 0.0f), (float)(RW - 1));
        float yr = fminf(fmaxf((float)y   + fy, 0.0f), (float)(RH - 1));
        float x0f = floorf(xr), y0f = floorf(yr);
        wxa[r] = xr - x0f;
        wya[r] = yr - y0f;
        int x0 = (int)x0f, y0 = (int)y0f;
        int x1 = min(x0 + 1, RW - 1);
        int y1 = min(y0 + 1, RH - 1);
        int ly0 = y0 - ys0, ly1 = y1 - ys0;
        if (((unsigned)ly0 < NS) && ((unsigned)ly1 < NS)) {
            unsigned b00 = (unsigned)(ly0 * RW + x0);
            unsigned b01 = (unsigned)(ly0 * RW + x1);
            unsigned b10 = (unsigned)(ly1 * RW + x0);
            unsigned b11 = (unsigned)(ly1 * RW + x1);
            pkA[r] = b00 | (b01 << 16);
            pkB[r] = b10 | (b11 << 16);
        } else {
            pkA[r] = 0xFFFFFFFFu;                // outlier sentinel
            pkB[r] = 0u;
        }
    }

    const float* imgc0 = img + ((size_t)b * RC + (size_t)cg * CPB) * RHW;
    float* outc0       = out + ((size_t)b * RC + (size_t)cg * CPB) * RHW;
    const float* gbase = imgc0 + (size_t)ys0 * RW;

    for (int c = 0; c < CPB; ++c) {
        // ---- Stage channel c's 20-row window: global -> LDS DMA ----
        const float* gc = gbase + (size_t)c * RHW;
        #pragma unroll
        for (int k = 0; k < NCHUNK; ++k) {
            int f = k * CHUNKF + (tid << 2);
            GLOAD_LDS16(gc + f, sm + f);
        }
        asm volatile("s_waitcnt vmcnt(0)" ::: "memory");
        __builtin_amdgcn_s_barrier();

        const float* p = imgc0 + (size_t)c * RHW;   // fallback plane
        float* q       = outc0 + (size_t)c * RHW;

        #pragma unroll
        for (int r = 0; r < ROWS; ++r) {
            float v;
            unsigned a = pkA[r];
            if (__builtin_expect(a != 0xFFFFFFFFu, 1)) {
                unsigned bb = pkB[r];
                float v00 = sm[a & 0xffffu];
                float v01 = sm[a >> 16];
                float v10 = sm[bb & 0xffffu];
                float v11 = sm[bb >> 16];
                float ax = wxa[r], ay = wya[r];
                float w00 = (1.0f - ax) * (1.0f - ay);
                float w01 = ax * (1.0f - ay);
                float w10 = (1.0f - ax) * ay;
                float w11 = ax * ay;
                v = v00 * w00 + v01 * w01 + v10 * w10 + v11 * w11;
            } else {
                // Cold outlier (|fy|>6): recompute and gather from global.
                int y = ybase + r;
                float fx = flb[(size_t)y * RW + tid];
                float fy = flb[RHW + (size_t)y * RW + tid];
                float xr = fminf(fmaxf((float)tid + fx, 0.0f), (float)(RW - 1));
                float yr = fminf(fmaxf((float)y   + fy, 0.0f), (float)(RH - 1));
                float x0f = floorf(xr), y0f = floorf(yr);
                float ax = xr - x0f, ay = yr - y0f;
                int x0 = (int)x0f, y0 = (int)y0f;
                int x1 = min(x0 + 1, RW - 1);
                int y1 = min(y0 + 1, RH - 1);
                float v00 = p[(size_t)y0 * RW + x0];
                float v01 = p[(size_t)y0 * RW + x1];
                float v10 = p[(size_t)y1 * RW + x0];
                float v11 = p[(size_t)y1 * RW + x1];
                v = v00 * (1.0f - ax) * (1.0f - ay) + v01 * ax * (1.0f - ay)
                  + v10 * (1.0f - ax) * ay          + v11 * ax * ay;
            }
            __builtin_nontemporal_store(v, q + (size_t)(ybase + r) * RW + tid);
        }

        // Buffer-free barrier: wait ds_reads only; stores stay in flight.
        asm volatile("s_waitcnt lgkmcnt(0)" ::: "memory");
        __builtin_amdgcn_s_barrier();
    }
}

extern "C" void kernel_launch(void* const* d_in, const int* in_sizes, int n_in,
                              void* d_out, int out_size, void* d_ws, size_t ws_size,
                              hipStream_t stream) {
    const float* img  = (const float*)d_in[0];
    const float* flow = (const float*)d_in[1];
    float* out = (float*)d_out;

    resample2d_kernel<<<NBLK, TPB, 0, stream>>>(img, flow, out);
}

// Round 7
// 178.973 us; speedup vs baseline: 2.5656x; 2.5656x over previous
//
#include <hip/hip_runtime.h>

// Resample2d: backward warp of input1 (B,C,H,W) by flow input2 (B,2,H,W).
// Bilinear, border padding (clamp). B=8 C=64 H=256 W=448, all fp32.
//
// Round 7: back to the R4 global-gather structure (179us) with the MLP fix.
// R4's VGPR_Count=28 showed the compiler serialized the gathers into ~6-deep
// load->wait->fma batches (latency-bound). Here each 8-channel batch issues
// all 32 gather loads into named register arrays before any use
// (sched_barrier(0) pins the boundary), giving ~32 outstanding loads/wave.
// 256-thr blocks, 16 ch/block, 14336 blocks, XCD-chunked swizzle, nt stores.

#define RB 8
#define RC 64
#define RH 256
#define RW 448
#define RHW (RH * RW)
#define THREADS 256
#define CS 4                         // channel split
#define CPB (RC / CS)                // 16 channels per block
#define SPI (RHW / THREADS)          // 448 strips per (image, cgroup)
#define NBLK (RB * CS * SPI)         // 14336 blocks
#define NXCD 8
#define BATCH 8                      // channels per load batch (32 loads)

__global__ __launch_bounds__(THREADS) void resample2d_kernel(
    const float* __restrict__ img,   // (B,C,H,W)
    const float* __restrict__ flow,  // (B,2,H,W)
    float* __restrict__ out)         // (B,C,H,W)
{
    // Bijective XCD-chunked swizzle: NBLK % NXCD == 0.
    int bid = blockIdx.x;
    const int chunk = NBLK / NXCD;                 // 1792
    int id = (bid & (NXCD - 1)) * chunk + (bid >> 3);

    // id = ((b*CS + cg) * SPI + strip): consecutive ids sweep contiguous
    // pixel strips of a fixed (b,cg) -> max row overlap within an XCD L2.
    int b  = id / (CS * SPI);
    int rm = id % (CS * SPI);
    int cg = rm / SPI;
    int pix = (rm % SPI) * THREADS + threadIdx.x;  // 0..RHW-1

    int x = pix % RW;
    int y = pix / RW;

    size_t fo = (size_t)b * 2 * RHW + pix;
    float fx = flow[fo];
    float fy = flow[fo + RHW];

    float xf = fminf(fmaxf((float)x + fx, 0.0f), (float)(RW - 1));
    float yf = fminf(fmaxf((float)y + fy, 0.0f), (float)(RH - 1));

    float x0f = floorf(xf);
    float y0f = floorf(yf);
    float wx = xf - x0f;
    float wy = yf - y0f;

    int x0 = (int)x0f;
    int y0 = (int)y0f;
    int x1 = min(x0 + 1, RW - 1);
    int y1 = min(y0 + 1, RH - 1);

    float w00 = (1.0f - wx) * (1.0f - wy);
    float w01 = wx * (1.0f - wy);
    float w10 = (1.0f - wx) * wy;
    float w11 = wx * wy;

    int o00 = y0 * RW + x0;
    int o01 = y0 * RW + x1;
    int o10 = y1 * RW + x0;
    int o11 = y1 * RW + x1;

    const float* imgb = img + ((size_t)b * RC + (size_t)cg * CPB) * RHW;
    float* outb = out + ((size_t)b * RC + (size_t)cg * CPB) * RHW + pix;

    #pragma unroll
    for (int cb = 0; cb < CPB; cb += BATCH) {
        float v00[BATCH], v01[BATCH], v10[BATCH], v11[BATCH];
        // Phase A: issue all 32 gather loads (kept above the barrier).
        #pragma unroll
        for (int c = 0; c < BATCH; ++c) {
            const float* p = imgb + (size_t)(cb + c) * RHW;
            v00[c] = p[o00];
            v01[c] = p[o01];
            v10[c] = p[o10];
            v11[c] = p[o11];
        }
        __builtin_amdgcn_sched_barrier(0);
        // Phase B: blend + streaming store.
        #pragma unroll
        for (int c = 0; c < BATCH; ++c) {
            float v = v00[c] * w00 + v01[c] * w01 + v10[c] * w10 + v11[c] * w11;
            __builtin_nontemporal_store(v, outb + (size_t)(cb + c) * RHW);
        }
    }
}

extern "C" void kernel_launch(void* const* d_in, const int* in_sizes, int n_in,
                              void* d_out, int out_size, void* d_ws, size_t ws_size,
                              hipStream_t stream) {
    const float* img  = (const float*)d_in[0];
    const float* flow = (const float*)d_in[1];
    float* out = (float*)d_out;

    resample2d_kernel<<<NBLK, THREADS, 0, stream>>>(img, flow, out);
}

// Round 8
// 129.344 us; speedup vs baseline: 3.5499x; 1.3837x over previous
//
#include <hip/hip_runtime.h>

// Resample2d: backward warp of input1 (B,C,H,W) by flow input2 (B,2,H,W).
// Bilinear, border padding (clamp). B=8 C=64 H=256 W=448, all fp32.
//
// Round 8: TA/L1 segment-throughput fix (measured 30 cyc/gather-instr =
// ~30 64B segments/wave-gather at 1 seg/cyc/CU).
//  (a) x-tap pairing: one dwordx2 per row-tap (4 gathers -> 2); border
//      x0=W-1 handled by base-1 shift + .y select (v01==v00 there).
//  (b) 16x4 per-wave pixel tiles (block = 16x16): gather footprint
//      ~10 rows x ~2 lines = ~20 segments/instr vs ~35 for 64x1 strips.
// Keeps: XCD-chunked bijective swizzle, 16 ch/block, nt stores.

#define RB 8
#define RC 64
#define RH 256
#define RW 448
#define RHW (RH * RW)
#define THREADS 256
#define CS 4                          // channel split
#define CPB (RC / CS)                 // 16 channels per block
#define TX 16                         // tile width (pixels)
#define TY 16                         // block tile height (4 waves x 4 rows)
#define XT (RW / TX)                  // 28
#define YTL (RH / TY)                 // 16
#define TILES (XT * YTL)              // 448 tiles per (image, cgroup)
#define NBLK (RB * CS * TILES)        // 14336 blocks
#define NXCD 8
#define BATCH 8                       // channels per load batch

__global__ __launch_bounds__(THREADS) void resample2d_kernel(
    const float* __restrict__ img,   // (B,C,H,W)
    const float* __restrict__ flow,  // (B,2,H,W)
    float* __restrict__ out)         // (B,C,H,W)
{
    // Bijective XCD-chunked swizzle: NBLK % NXCD == 0.
    int bid = blockIdx.x;
    const int chunk = NBLK / NXCD;                 // 1792
    int id = (bid & (NXCD - 1)) * chunk + (bid >> 3);

    // id = ((b*CS + cg) * TILES + tile), tiles row-major within the image:
    // consecutive ids share rows/columns -> XCD-L2 locality.
    int b  = id / (CS * TILES);
    int rm = id % (CS * TILES);
    int cg = rm / TILES;
    int t  = rm % TILES;
    int tx0 = (t % XT) * TX;
    int ty0 = (t / XT) * TY;

    int tid = threadIdx.x;
    int x = tx0 + (tid & (TX - 1));
    int y = ty0 + (tid >> 4);        // wave w covers rows [4w,4w+4) x 16 cols

    size_t fo = (size_t)b * 2 * RHW + (size_t)y * RW + x;
    float fx = flow[fo];
    float fy = flow[fo + RHW];

    float xf = fminf(fmaxf((float)x + fx, 0.0f), (float)(RW - 1));
    float yf = fminf(fmaxf((float)y + fy, 0.0f), (float)(RH - 1));

    float x0f = floorf(xf);
    float y0f = floorf(yf);
    float wx = xf - x0f;
    float wy = yf - y0f;

    int x0 = (int)x0f;
    int y0 = (int)y0f;
    int y1 = min(y0 + 1, RH - 1);
    int shift = (x0 == RW - 1) ? 1 : 0;   // border: x1==x0

    float w00 = (1.0f - wx) * (1.0f - wy);
    float w01 = wx * (1.0f - wy);
    float w10 = (1.0f - wx) * wy;
    float w11 = wx * wy;

    int o0 = y0 * RW + x0 - shift;        // pair covers {x0-shift, x0-shift+1}
    int o1 = y1 * RW + x0 - shift;

    const float* imgb = img + ((size_t)b * RC + (size_t)cg * CPB) * RHW;
    float* outb = out + ((size_t)b * RC + (size_t)cg * CPB) * RHW
                      + (size_t)y * RW + x;

    #pragma unroll
    for (int cb = 0; cb < CPB; cb += BATCH) {
        float2 dA[BATCH], dB[BATCH];
        // Phase A: issue all 16 paired gathers.
        #pragma unroll
        for (int c = 0; c < BATCH; ++c) {
            const float* p = imgb + (size_t)(cb + c) * RHW;
            dA[c] = *(const float2*)(p + o0);
            dB[c] = *(const float2*)(p + o1);
        }
        __builtin_amdgcn_sched_barrier(0);
        // Phase B: blend + streaming store.
        #pragma unroll
        for (int c = 0; c < BATCH; ++c) {
            float v00 = shift ? dA[c].y : dA[c].x;
            float v01 = dA[c].y;
            float v10 = shift ? dB[c].y : dB[c].x;
            float v11 = dB[c].y;
            float v = v00 * w00 + v01 * w01 + v10 * w10 + v11 * w11;
            __builtin_nontemporal_store(v, outb + (size_t)(cb + c) * RHW);
        }
    }
}

extern "C" void kernel_launch(void* const* d_in, const int* in_sizes, int n_in,
                              void* d_out, int out_size, void* d_ws, size_t ws_size,
                              hipStream_t stream) {
    const float* img  = (const float*)d_in[0];
    const float* flow = (const float*)d_in[1];
    float* out = (float*)d_out;

    resample2d_kernel<<<NBLK, THREADS, 0, stream>>>(img, flow, out);
}

// Round 9
// 126.804 us; speedup vs baseline: 3.6211x; 1.0200x over previous
//
#include <hip/hip_runtime.h>

// Resample2d: backward warp of input1 (B,C,H,W) by flow input2 (B,2,H,W).
// Bilinear, border padding (clamp). B=8 C=64 H=256 W=448, all fp32.
//
// Round 9: R8 confirmed TA-segment-bound gathers. Fixes:
//  (a) TX=32 x TY=8 tiles, wave = 32x2 pixels: each wave store-row is one
//      full aligned 128B line -> kills the 1.29x HBM write amplification
//      that 64B nt-stores caused (WRITE_SIZE 295 -> 229 MB).
//  (b) border handled by weight-folding (wx==0 at the clamp edge), so the
//      inner loop has no per-channel selects: always blend dA.x/dA.y.
// Keeps: x-tap pairing (dwordx2), 16 ch/block, batch-8 phased gathers,
// XCD-chunked bijective swizzle, nt stores.

#define RB 8
#define RC 64
#define RH 256
#define RW 448
#define RHW (RH * RW)
#define THREADS 256
#define CS 4                          // channel split
#define CPB (RC / CS)                 // 16 channels per block
#define TX 32                         // tile width (pixels)
#define TY 8                          // block tile height (4 waves x 2 rows)
#define XT (RW / TX)                  // 14
#define YTL (RH / TY)                 // 32
#define TILES (XT * YTL)              // 448 tiles per (image, cgroup)
#define NBLK (RB * CS * TILES)        // 14336 blocks
#define NXCD 8
#define BATCH 8                       // channels per load batch

__global__ __launch_bounds__(THREADS) void resample2d_kernel(
    const float* __restrict__ img,   // (B,C,H,W)
    const float* __restrict__ flow,  // (B,2,H,W)
    float* __restrict__ out)         // (B,C,H,W)
{
    // Bijective XCD-chunked swizzle: NBLK % NXCD == 0.
    int bid = blockIdx.x;
    const int chunk = NBLK / NXCD;                 // 1792
    int id = (bid & (NXCD - 1)) * chunk + (bid >> 3);

    // id = ((b*CS + cg) * TILES + tile), tiles row-major within the image.
    int b  = id / (CS * TILES);
    int rm = id % (CS * TILES);
    int cg = rm / TILES;
    int t  = rm % TILES;
    int tx0 = (t % XT) * TX;
    int ty0 = (t / XT) * TY;

    int tid = threadIdx.x;
    int x = tx0 + (tid & (TX - 1));
    int y = ty0 + (tid >> 5);        // wave w covers rows {2w,2w+1} x 32 cols

    size_t fo = (size_t)b * 2 * RHW + (size_t)y * RW + x;
    float fx = flow[fo];
    float fy = flow[fo + RHW];

    float xf = fminf(fmaxf((float)x + fx, 0.0f), (float)(RW - 1));
    float yf = fminf(fmaxf((float)y + fy, 0.0f), (float)(RH - 1));

    float x0f = floorf(xf);
    float y0f = floorf(yf);
    float wx = xf - x0f;
    float wy = yf - y0f;

    int x0 = (int)x0f;
    int y0 = (int)y0f;
    int y1 = min(y0 + 1, RH - 1);
    int shift = (x0 == RW - 1) ? 1 : 0;   // border: wx==0 there

    float w00 = (1.0f - wx) * (1.0f - wy);
    float w01 = wx * (1.0f - wy);
    float w10 = (1.0f - wx) * wy;
    float w11 = wx * wy;
    if (shift) {                     // fold border into weights: dA.y is x0
        w01 += w00; w00 = 0.0f;      // (wx==0 so w01,w11 were 0; now the
        w11 += w10; w10 = 0.0f;      //  .y slot carries the full weight)
    }

    int o0 = y0 * RW + x0 - shift;        // pair covers {x0-shift, x0-shift+1}
    int o1 = y1 * RW + x0 - shift;

    const float* imgb = img + ((size_t)b * RC + (size_t)cg * CPB) * RHW;
    float* outb = out + ((size_t)b * RC + (size_t)cg * CPB) * RHW
                      + (size_t)y * RW + x;

    #pragma unroll
    for (int cb = 0; cb < CPB; cb += BATCH) {
        float2 dA[BATCH], dB[BATCH];
        // Phase A: issue all 16 paired gathers.
        #pragma unroll
        for (int c = 0; c < BATCH; ++c) {
            const float* p = imgb + (size_t)(cb + c) * RHW;
            dA[c] = *(const float2*)(p + o0);
            dB[c] = *(const float2*)(p + o1);
        }
        __builtin_amdgcn_sched_barrier(0);
        // Phase B: blend + full-line streaming store.
        #pragma unroll
        for (int c = 0; c < BATCH; ++c) {
            float v = dA[c].x * w00 + dA[c].y * w01
                    + dB[c].x * w10 + dB[c].y * w11;
            __builtin_nontemporal_store(v, outb + (size_t)(cb + c) * RHW);
        }
    }
}

extern "C" void kernel_launch(void* const* d_in, const int* in_sizes, int n_in,
                              void* d_out, int out_size, void* d_ws, size_t ws_size,
                              hipStream_t stream) {
    const float* img  = (const float*)d_in[0];
    const float* flow = (const float*)d_in[1];
    float* out = (float*)d_out;

    resample2d_kernel<<<NBLK, THREADS, 0, stream>>>(img, flow, out);
}